// Round 11
// baseline (340.407 us; speedup 1.0000x reference)
//
#include <hip/hip_runtime.h>
#include <math.h>

#define N_NODES 50000
#define N_EDGES 800000
#define HEADS 4
#define N_GRAPHS 64
#define NEG_SLOPE 0.2f
#define LOG2E 1.4426950408889634f
#define SCAN_NB 196            // 196*256 = 50176 >= N_NODES
#define POOL_CHUNK 200
#define POOL_NB 250            // 250*200 = 50000 exactly
#define FEAT_NB 1563           // ceil(50000/32)
#define EDGE_Q 200000          // N_EDGES/4: 4 edges per thread
#define EDGE_NB 782            // ceil(200000/256)

// monotone float<->uint key for atomicMax-based segment max (pooling).
__device__ __forceinline__ unsigned fkey(float f) {
    unsigned u = __float_as_uint(f);
    return (u & 0x80000000u) ? ~u : (u | 0x80000000u);
}
__device__ __forceinline__ float kval(unsigned k) {
    unsigned u = (k & 0x80000000u) ? (k & 0x7FFFFFFFu) : ~k;
    return __uint_as_float(u);
}

// f32 -> bf16 (RNE), two packed into one uint (lo = first channel)
__device__ __forceinline__ unsigned short f2bf(float f) {
    unsigned u = __float_as_uint(f);
    u += 0x7FFFu + ((u >> 16) & 1u);
    return (unsigned short)(u >> 16);
}
__device__ __forceinline__ unsigned pack_bf2(float a, float b) {
    return (unsigned)f2bf(a) | ((unsigned)f2bf(b) << 16);
}

// ---------------- CSR build (counting sort by dst, rank-based) ----------------

// deg histogram + per-edge rank within its dst segment. 4 edges/thread (ILP).
__global__ void hist_kernel(const int* __restrict__ dst, int* __restrict__ deg,
                            int* __restrict__ rank) {
    int i = blockIdx.x * 256 + threadIdx.x;
    if (i >= EDGE_Q) return;
    int e0 = i, e1 = i + EDGE_Q, e2 = i + 2 * EDGE_Q, e3 = i + 3 * EDGE_Q;
    int d0 = dst[e0], d1 = dst[e1], d2 = dst[e2], d3 = dst[e3];
    int r0 = atomicAdd(&deg[d0], 1);
    int r1 = atomicAdd(&deg[d1], 1);
    int r2 = atomicAdd(&deg[d2], 1);
    int r3 = atomicAdd(&deg[d3], 1);
    rank[e0] = r0; rank[e1] = r1; rank[e2] = r2; rank[e3] = r3;
}

// per-block sums of deg (256 elements/block)
__global__ void partial_kernel(const int* __restrict__ deg, int* __restrict__ partial) {
    int t = threadIdx.x, b = blockIdx.x;
    int i = b * 256 + t;
    int v = (i < N_NODES) ? deg[i] : 0;
    #pragma unroll
    for (int off = 1; off < 64; off <<= 1) v += __shfl_xor(v, off, 64);
    __shared__ int wsum[4];
    if ((t & 63) == 0) wsum[t >> 6] = v;
    __syncthreads();
    if (t == 0) partial[b] = wsum[0] + wsum[1] + wsum[2] + wsum[3];
}

// block-level exclusive scan of deg -> row_start; block offset computed by
// redundantly scanning partial[SCAN_NB] inside every block (cheap, -1 dispatch).
__global__ void csr_offsets_kernel(const int* __restrict__ deg, const int* __restrict__ partial,
                                   int* __restrict__ row_start) {
    __shared__ int sb[SCAN_NB];
    __shared__ int wsumA[4];
    __shared__ int wsumB[4];
    int t = threadIdx.x, b = blockIdx.x;
    int lane = t & 63, w = t >> 6;
    {   // exclusive scan of partial -> sb
        int v = (t < SCAN_NB) ? partial[t] : 0;
        int incl = v;
        #pragma unroll
        for (int off = 1; off < 64; off <<= 1) {
            int u = __shfl_up(incl, off, 64);
            if (lane >= off) incl += u;
        }
        if (lane == 63) wsumA[w] = incl;
        __syncthreads();
        int woff = 0;
        #pragma unroll
        for (int k = 0; k < 4; ++k) if (k < w) woff += wsumA[k];
        if (t < SCAN_NB) sb[t] = woff + incl - v;
        __syncthreads();
    }
    int i = b * 256 + t;
    int v = (i < N_NODES) ? deg[i] : 0;
    int incl = v;
    #pragma unroll
    for (int off = 1; off < 64; off <<= 1) {
        int u = __shfl_up(incl, off, 64);
        if (lane >= off) incl += u;
    }
    if (lane == 63) wsumB[w] = incl;
    __syncthreads();
    int woff = sb[b];
    #pragma unroll
    for (int k = 0; k < 4; ++k) if (k < w) woff += wsumB[k];
    int excl = woff + incl - v;
    if (i < N_NODES) row_start[i] = excl;
    else if (i == N_NODES) row_start[i] = excl;   // == N_EDGES
}

// atomic-free scatter: pos = row_start[dst] + rank. 4 edges/thread (ILP).
__global__ void scatter_kernel(const int* __restrict__ src, const int* __restrict__ dst,
                               const int* __restrict__ rank, const int* __restrict__ row_start,
                               int* __restrict__ csr_src) {
    int i = blockIdx.x * 256 + threadIdx.x;
    if (i >= EDGE_Q) return;
    int e0 = i, e1 = i + EDGE_Q, e2 = i + 2 * EDGE_Q, e3 = i + 3 * EDGE_Q;
    int d0 = dst[e0], d1 = dst[e1], d2 = dst[e2], d3 = dst[e3];
    int k0 = rank[e0], k1 = rank[e1], k2 = rank[e2], k3 = rank[e3];
    int s0 = src[e0], s1 = src[e1], s2 = src[e2], s3 = src[e3];
    int p0 = row_start[d0] + k0;
    int p1 = row_start[d1] + k1;
    int p2 = row_start[d2] + k2;
    int p3 = row_start[d3] + k3;
    csr_src[p0] = s0;
    csr_src[p1] = s1;
    csr_src[p2] = s2;
    csr_src[p3] = s3;
}

// ---------------- node pipeline ----------------

// feat = h @ W (128x128). Register-tiled: 32 nodes/block, 256 threads,
// thread = (ng 0..7, cg 0..31) computes 4 nodes x 4 channels.
// Layer 0: wid != nullptr -> rows gathered from emb[wid[n]] during staging.
// el/er stored PRE-SCALED by log2(e) so gat_aggregate uses native exp2.
__global__ __launch_bounds__(256, 2)
void feat_kernel(const float* __restrict__ h, const int* __restrict__ wid,
                 const float* __restrict__ W,
                 const float* __restrict__ al, const float* __restrict__ ar,
                 unsigned* __restrict__ featb, float* __restrict__ el,
                 float* __restrict__ er) {
    __shared__ float Wl[128 * 128];      // 64 KB
    __shared__ float hl[32 * 128];       // 16 KB
    int t = threadIdx.x;
    {   // stage W: 4096 float4 / 256 threads = 16 each
        const float4* W4 = (const float4*)W;
        float4* Wl4 = (float4*)Wl;
        #pragma unroll
        for (int i = 0; i < 16; ++i) Wl4[t + 256 * i] = W4[t + 256 * i];
    }
    int n0 = blockIdx.x * 32;
    {   // stage h tile: 1024 float4 / 256 threads = 4 each (zero-fill tail)
        const float4* h4 = (const float4*)h;
        float4* hl4 = (float4*)hl;
        #pragma unroll
        for (int r = 0; r < 4; ++r) {
            int i = t + 256 * r;
            int n = i >> 5, q = i & 31;
            float4 v = {0.f, 0.f, 0.f, 0.f};
            int gn = n0 + n;
            if (gn < N_NODES) {
                int row = wid ? wid[gn] : gn;
                v = h4[(size_t)row * 32 + q];
            }
            hl4[n * 32 + q] = v;
        }
    }
    __syncthreads();
    int ng = t >> 5, cg = t & 31;
    const float4* hl4 = (const float4*)hl;
    const float4* Wl4 = (const float4*)Wl;
    float4 acc[4];
    #pragma unroll
    for (int i = 0; i < 4; ++i) acc[i] = {0.f, 0.f, 0.f, 0.f};
    for (int k4 = 0; k4 < 32; ++k4) {
        float4 a0 = hl4[(ng * 4 + 0) * 32 + k4];
        float4 a1 = hl4[(ng * 4 + 1) * 32 + k4];
        float4 a2 = hl4[(ng * 4 + 2) * 32 + k4];
        float4 a3 = hl4[(ng * 4 + 3) * 32 + k4];
        #pragma unroll
        for (int kk = 0; kk < 4; ++kk) {
            float4 w = Wl4[(k4 * 4 + kk) * 32 + cg];
            float c0 = ((const float*)&a0)[kk];
            float c1 = ((const float*)&a1)[kk];
            float c2 = ((const float*)&a2)[kk];
            float c3 = ((const float*)&a3)[kk];
            acc[0].x += c0 * w.x; acc[0].y += c0 * w.y; acc[0].z += c0 * w.z; acc[0].w += c0 * w.w;
            acc[1].x += c1 * w.x; acc[1].y += c1 * w.y; acc[1].z += c1 * w.z; acc[1].w += c1 * w.w;
            acc[2].x += c2 * w.x; acc[2].y += c2 * w.y; acc[2].z += c2 * w.z; acc[2].w += c2 * w.w;
            acc[3].x += c3 * w.x; acc[3].y += c3 * w.y; acc[3].z += c3 * w.z; acc[3].w += c3 * w.w;
        }
    }
    int hd = cg >> 3;            // head of this 4-channel group
    float a0v = al[cg * 4], a1v = al[cg * 4 + 1], a2v = al[cg * 4 + 2], a3v = al[cg * 4 + 3];
    float r0v = ar[cg * 4], r1v = ar[cg * 4 + 1], r2v = ar[cg * 4 + 2], r3v = ar[cg * 4 + 3];
    #pragma unroll
    for (int i = 0; i < 4; ++i) {
        int n = n0 + ng * 4 + i;
        if (n >= N_NODES) break;             // uniform across the 8-lane head group
        uint2 pk;
        pk.x = pack_bf2(acc[i].x, acc[i].y);
        pk.y = pack_bf2(acc[i].z, acc[i].w);
        *(uint2*)(featb + (size_t)n * 64 + cg * 2) = pk;
        float pl = acc[i].x * a0v + acc[i].y * a1v + acc[i].z * a2v + acc[i].w * a3v;
        float pr = acc[i].x * r0v + acc[i].y * r1v + acc[i].z * r2v + acc[i].w * r3v;
        #pragma unroll
        for (int off = 1; off < 8; off <<= 1) {
            pl += __shfl_xor(pl, off, 64);
            pr += __shfl_xor(pr, off, 64);
        }
        if ((t & 7) == 0) {
            el[n * 4 + hd] = pl * LOG2E;     // pre-scaled for exp2 in aggregate
            er[n * 4 + hd] = pr * LOG2E;
        }
    }
}

// Fused softmax + aggregation + ELU. One 64-lane wave per dst node.
// Half-wave edge pairing: lanes [0,32) handle edge base+half, each lane owns
// 4 channels (uint2) of head hc=(lane&31)>>3 -> exp redundancy 8x (was 16x),
// wave processes 2 edges/iter (4 with unroll). No cross-lane ops in the loop;
// one shfl_xor(32) pair-reduce at the end. el/er pre-scaled -> native exp2f.
__global__ void gat_aggregate(const int* __restrict__ row_start, const int* __restrict__ csr_src,
                              const unsigned* __restrict__ featb, const float* __restrict__ el,
                              const float* __restrict__ er, float* __restrict__ hout) {
    int lane = threadIdx.x & 63;
    int d = blockIdx.x * 4 + (threadIdx.x >> 6);
    int beg = row_start[d], end = row_start[d + 1];
    int half = lane >> 5;        // edge parity within a pair
    int lw = lane & 31;          // channels [4lw, 4lw+4)
    int hc = lw >> 3;            // head of this lane's channels
    float er_h = er[d * 4 + hc];
    float4 acc = {0.f, 0.f, 0.f, 0.f};
    float dsum = 0.f;
    int nmain = (end - beg) & ~3;
    int bend = beg + nmain;
    for (int base = beg; base < bend; base += 4) {
        int ea = base + half, eb = base + 2 + half;
        int sa = csr_src[ea];
        int sb = csr_src[eb];
        float la = el[sa * 4 + hc];
        float lb = el[sb * 4 + hc];
        uint2 pa = *(const uint2*)(featb + (size_t)sa * 64 + lw * 2);
        uint2 pb = *(const uint2*)(featb + (size_t)sb * 64 + lw * 2);
        float va = la + er_h; va = fmaxf(va, NEG_SLOPE * va);
        float vb = lb + er_h; vb = fmaxf(vb, NEG_SLOPE * vb);
        float xa = exp2f(va), xb = exp2f(vb);
        dsum += xa + xb;
        acc.x += __uint_as_float(pa.x << 16) * xa;
        acc.y += __uint_as_float(pa.x & 0xFFFF0000u) * xa;
        acc.z += __uint_as_float(pa.y << 16) * xa;
        acc.w += __uint_as_float(pa.y & 0xFFFF0000u) * xa;
        acc.x += __uint_as_float(pb.x << 16) * xb;
        acc.y += __uint_as_float(pb.x & 0xFFFF0000u) * xb;
        acc.z += __uint_as_float(pb.y << 16) * xb;
        acc.w += __uint_as_float(pb.y & 0xFFFF0000u) * xb;
    }
    for (int ee = bend + half; ee < end; ee += 2) {
        int s = csr_src[ee];
        float lv = el[s * 4 + hc];
        uint2 pv = *(const uint2*)(featb + (size_t)s * 64 + lw * 2);
        float v = lv + er_h; v = fmaxf(v, NEG_SLOPE * v);
        float x = exp2f(v);
        dsum += x;
        acc.x += __uint_as_float(pv.x << 16) * x;
        acc.y += __uint_as_float(pv.x & 0xFFFF0000u) * x;
        acc.z += __uint_as_float(pv.y << 16) * x;
        acc.w += __uint_as_float(pv.y & 0xFFFF0000u) * x;
    }
    // combine the two halves (same channels, disjoint edge subsets)
    acc.x += __shfl_xor(acc.x, 32, 64);
    acc.y += __shfl_xor(acc.y, 32, 64);
    acc.z += __shfl_xor(acc.z, 32, 64);
    acc.w += __shfl_xor(acc.w, 32, 64);
    dsum  += __shfl_xor(dsum, 32, 64);
    if (half == 0) {
        float inv = 1.f / (dsum + 1e-10f);
        float o0 = acc.x * inv, o1 = acc.y * inv, o2 = acc.z * inv, o3 = acc.w * inv;
        o0 = o0 > 0.f ? o0 : expm1f(o0);
        o1 = o1 > 0.f ? o1 : expm1f(o1);
        o2 = o2 > 0.f ? o2 : expm1f(o2);
        o3 = o3 > 0.f ? o3 : expm1f(o3);
        float4 o = {o0, o1, o2, o3};
        ((float4*)(hout + (size_t)d * 128))[lw] = o;
    }
}

// ---------------- pooling / loss ----------------

__global__ void pool_kernel(const int* __restrict__ gid, const float* __restrict__ h,
                            unsigned* __restrict__ pkeys) {
    int t = threadIdx.x;
    int c = t & 127;
    int par = t >> 7;              // 0/1
    int n0 = blockIdx.x * POOL_CHUNK;
    float m = 0.f;
    int cur_g = -1;
    for (int n = n0 + par; n < n0 + POOL_CHUNK; n += 2) {
        int g = gid[n];
        if (g != cur_g) {
            if (cur_g >= 0) atomicMax(&pkeys[cur_g * 128 + c], fkey(m));
            cur_g = g;
            m = -3.0e38f;
        }
        m = fmaxf(m, h[(size_t)n * 128 + c]);
    }
    if (cur_g >= 0) atomicMax(&pkeys[cur_g * 128 + c], fkey(m));
}

__global__ void logits_kernel(const unsigned* __restrict__ pkeys, const float* __restrict__ w,
                              const float* __restrict__ bptr, float* __restrict__ logits) {
    int g = blockIdx.x, t = threadIdx.x;      // 64 blocks x 64 threads
    float sum = 0.f;
    for (int c = t; c < 128; c += 64) {
        unsigned k = pkeys[g * 128 + c];
        float v = (k == 0u) ? 0.f : kval(k);
        sum += v * w[c];
    }
    #pragma unroll
    for (int off = 32; off; off >>= 1) sum += __shfl_down(sum, off, 64);
    if (t == 0) logits[g] = sum + bptr[0];
}

__global__ void final_kernel(const float* __restrict__ logits, const float* __restrict__ y,
                             float* __restrict__ out) {
    int t = threadIdx.x;  // 64
    float l = logits[t];
    float term = fmaxf(l, 0.f) - l * y[t] + log1pf(expf(-fabsf(l)));
    float s = term;
    #pragma unroll
    for (int off = 32; off; off >>= 1) s += __shfl_down(s, off, 64);
    out[1 + t] = 1.f / (1.f + expf(-l));
    if (t == 0) out[0] = s * (1.f / 64.f);
}

extern "C" void kernel_launch(void* const* d_in, const int* in_sizes, int n_in,
                              void* d_out, int out_size, void* d_ws, size_t ws_size,
                              hipStream_t stream) {
    const int* word_ids  = (const int*)d_in[0];
    const int* esrc      = (const int*)d_in[1];
    const int* edst      = (const int*)d_in[2];
    const int* gid       = (const int*)d_in[3];
    const float* y_data  = (const float*)d_in[4];
    const float* emb     = (const float*)d_in[5];
    const float* W0      = (const float*)d_in[6];
    const float* al0     = (const float*)d_in[7];
    const float* ar0     = (const float*)d_in[8];
    const float* W1      = (const float*)d_in[9];
    const float* al1     = (const float*)d_in[10];
    const float* ar1     = (const float*)d_in[11];
    const float* out_w   = (const float*)d_in[12];
    const float* out_b   = (const float*)d_in[13];
    float* out = (float*)d_out;

    // workspace layout (float offsets); ~47 MB total
    float* ws = (float*)d_ws;
    unsigned* featb  = (unsigned*)ws;                // N*64 uints = 3,200,000
    float*    hbuf   = ws + 3200000;                 // N*128 = 6,400,000
    float*    el     = ws + 9600000;                 // 200,000
    float*    er     = ws + 9800000;                 // 200,000
    int*      row_st = (int*)(ws + 10000000);        // 50,001
    int*      deg    = (int*)(ws + 10051000);        // 50,000
    int*      rank   = (int*)(ws + 10101000);        // 800,000
    int*      csrsrc = (int*)(ws + 10901000);        // 800,000
    int*      partial= (int*)(ws + 11701000);        // 196
    unsigned* pkeys  = (unsigned*)(ws + 11701400);   // 8,192
    float*    logits = ws + 11709592;                // 64

    // CSR build (shared by both layers)
    hipMemsetAsync(deg, 0, (size_t)N_NODES * 4, stream);
    hist_kernel<<<EDGE_NB, 256, 0, stream>>>(edst, deg, rank);
    partial_kernel<<<SCAN_NB, 256, 0, stream>>>(deg, partial);
    csr_offsets_kernel<<<SCAN_NB, 256, 0, stream>>>(deg, partial, row_st);
    scatter_kernel<<<EDGE_NB, 256, 0, stream>>>(esrc, edst, rank, row_st, csrsrc);

    // layer 0 (gather fused into feat staging), then layer 1
    feat_kernel<<<FEAT_NB, 256, 0, stream>>>(emb, word_ids, W0, al0, ar0, featb, el, er);
    gat_aggregate<<<12500, 256, 0, stream>>>(row_st, csrsrc, featb, el, er, hbuf);
    feat_kernel<<<FEAT_NB, 256, 0, stream>>>(hbuf, nullptr, W1, al1, ar1, featb, el, er);
    gat_aggregate<<<12500, 256, 0, stream>>>(row_st, csrsrc, featb, el, er, hbuf);

    hipMemsetAsync(pkeys, 0, (size_t)N_GRAPHS * 128 * 4, stream);
    pool_kernel<<<POOL_NB, 256, 0, stream>>>(gid, hbuf, pkeys);
    logits_kernel<<<N_GRAPHS, 64, 0, stream>>>(pkeys, out_w, out_b, logits);
    final_kernel<<<1, 64, 0, stream>>>(logits, y_data, out);
}

// Round 12
// 329.444 us; speedup vs baseline: 1.0333x; 1.0333x over previous
//
#include <hip/hip_runtime.h>
#include <math.h>

#define N_NODES 50000
#define N_EDGES 800000
#define HEADS 4
#define N_GRAPHS 64
#define NEG_SLOPE 0.2f
#define LOG2E 1.4426950408889634f
#define SCAN_NB 196            // 196*256 = 50176 >= N_NODES
#define POOL_CHUNK 200
#define POOL_NB 250            // 250*200 = 50000 exactly
#define FEAT_NB 1563           // ceil(50000/32)
#define EDGE_Q 200000          // N_EDGES/4: 4 edges per thread
#define EDGE_NB 782            // ceil(200000/256)

// monotone float<->uint key for atomicMax-based segment max (pooling).
__device__ __forceinline__ unsigned fkey(float f) {
    unsigned u = __float_as_uint(f);
    return (u & 0x80000000u) ? ~u : (u | 0x80000000u);
}
__device__ __forceinline__ float kval(unsigned k) {
    unsigned u = (k & 0x80000000u) ? (k & 0x7FFFFFFFu) : ~k;
    return __uint_as_float(u);
}

// f32 -> bf16 (RNE), two packed into one uint (lo = first channel)
__device__ __forceinline__ unsigned short f2bf(float f) {
    unsigned u = __float_as_uint(f);
    u += 0x7FFFu + ((u >> 16) & 1u);
    return (unsigned short)(u >> 16);
}
__device__ __forceinline__ unsigned pack_bf2(float a, float b) {
    return (unsigned)f2bf(a) | ((unsigned)f2bf(b) << 16);
}

// ---------------- CSR build (counting sort by dst, rank-based) ----------------

// deg histogram + per-edge rank within its dst segment. 4 edges/thread (ILP).
__global__ void hist_kernel(const int* __restrict__ dst, int* __restrict__ deg,
                            int* __restrict__ rank) {
    int i = blockIdx.x * 256 + threadIdx.x;
    if (i >= EDGE_Q) return;
    int e0 = i, e1 = i + EDGE_Q, e2 = i + 2 * EDGE_Q, e3 = i + 3 * EDGE_Q;
    int d0 = dst[e0], d1 = dst[e1], d2 = dst[e2], d3 = dst[e3];
    int r0 = atomicAdd(&deg[d0], 1);
    int r1 = atomicAdd(&deg[d1], 1);
    int r2 = atomicAdd(&deg[d2], 1);
    int r3 = atomicAdd(&deg[d3], 1);
    rank[e0] = r0; rank[e1] = r1; rank[e2] = r2; rank[e3] = r3;
}

// per-block sums of deg (256 elements/block)
__global__ void partial_kernel(const int* __restrict__ deg, int* __restrict__ partial) {
    int t = threadIdx.x, b = blockIdx.x;
    int i = b * 256 + t;
    int v = (i < N_NODES) ? deg[i] : 0;
    #pragma unroll
    for (int off = 1; off < 64; off <<= 1) v += __shfl_xor(v, off, 64);
    __shared__ int wsum[4];
    if ((t & 63) == 0) wsum[t >> 6] = v;
    __syncthreads();
    if (t == 0) partial[b] = wsum[0] + wsum[1] + wsum[2] + wsum[3];
}

// block-level exclusive scan of deg -> row_start; block offset computed by
// redundantly scanning partial[SCAN_NB] inside every block (cheap, -1 dispatch).
__global__ void csr_offsets_kernel(const int* __restrict__ deg, const int* __restrict__ partial,
                                   int* __restrict__ row_start) {
    __shared__ int sb[SCAN_NB];
    __shared__ int wsumA[4];
    __shared__ int wsumB[4];
    int t = threadIdx.x, b = blockIdx.x;
    int lane = t & 63, w = t >> 6;
    {   // exclusive scan of partial -> sb
        int v = (t < SCAN_NB) ? partial[t] : 0;
        int incl = v;
        #pragma unroll
        for (int off = 1; off < 64; off <<= 1) {
            int u = __shfl_up(incl, off, 64);
            if (lane >= off) incl += u;
        }
        if (lane == 63) wsumA[w] = incl;
        __syncthreads();
        int woff = 0;
        #pragma unroll
        for (int k = 0; k < 4; ++k) if (k < w) woff += wsumA[k];
        if (t < SCAN_NB) sb[t] = woff + incl - v;
        __syncthreads();
    }
    int i = b * 256 + t;
    int v = (i < N_NODES) ? deg[i] : 0;
    int incl = v;
    #pragma unroll
    for (int off = 1; off < 64; off <<= 1) {
        int u = __shfl_up(incl, off, 64);
        if (lane >= off) incl += u;
    }
    if (lane == 63) wsumB[w] = incl;
    __syncthreads();
    int woff = sb[b];
    #pragma unroll
    for (int k = 0; k < 4; ++k) if (k < w) woff += wsumB[k];
    int excl = woff + incl - v;
    if (i < N_NODES) row_start[i] = excl;
    else if (i == N_NODES) row_start[i] = excl;   // == N_EDGES
}

// atomic-free scatter: pos = row_start[dst] + rank. 4 edges/thread (ILP).
__global__ void scatter_kernel(const int* __restrict__ src, const int* __restrict__ dst,
                               const int* __restrict__ rank, const int* __restrict__ row_start,
                               int* __restrict__ csr_src) {
    int i = blockIdx.x * 256 + threadIdx.x;
    if (i >= EDGE_Q) return;
    int e0 = i, e1 = i + EDGE_Q, e2 = i + 2 * EDGE_Q, e3 = i + 3 * EDGE_Q;
    int d0 = dst[e0], d1 = dst[e1], d2 = dst[e2], d3 = dst[e3];
    int k0 = rank[e0], k1 = rank[e1], k2 = rank[e2], k3 = rank[e3];
    int s0 = src[e0], s1 = src[e1], s2 = src[e2], s3 = src[e3];
    int p0 = row_start[d0] + k0;
    int p1 = row_start[d1] + k1;
    int p2 = row_start[d2] + k2;
    int p3 = row_start[d3] + k3;
    csr_src[p0] = s0;
    csr_src[p1] = s1;
    csr_src[p2] = s2;
    csr_src[p3] = s3;
}

// ---------------- node pipeline ----------------

// feat = h @ W (128x128). Register-tiled: 32 nodes/block, 256 threads,
// thread = (ng 0..7, cg 0..31) computes 4 nodes x 4 channels.
// Layer 0: wid != nullptr -> rows gathered from emb[wid[n]] during staging.
// el/er stored PRE-SCALED by log2(e) so gat_aggregate uses native exp2.
__global__ __launch_bounds__(256, 2)
void feat_kernel(const float* __restrict__ h, const int* __restrict__ wid,
                 const float* __restrict__ W,
                 const float* __restrict__ al, const float* __restrict__ ar,
                 unsigned* __restrict__ featb, float* __restrict__ el,
                 float* __restrict__ er) {
    __shared__ float Wl[128 * 128];      // 64 KB
    __shared__ float hl[32 * 128];       // 16 KB
    int t = threadIdx.x;
    {   // stage W: 4096 float4 / 256 threads = 16 each
        const float4* W4 = (const float4*)W;
        float4* Wl4 = (float4*)Wl;
        #pragma unroll
        for (int i = 0; i < 16; ++i) Wl4[t + 256 * i] = W4[t + 256 * i];
    }
    int n0 = blockIdx.x * 32;
    {   // stage h tile: 1024 float4 / 256 threads = 4 each (zero-fill tail)
        const float4* h4 = (const float4*)h;
        float4* hl4 = (float4*)hl;
        #pragma unroll
        for (int r = 0; r < 4; ++r) {
            int i = t + 256 * r;
            int n = i >> 5, q = i & 31;
            float4 v = {0.f, 0.f, 0.f, 0.f};
            int gn = n0 + n;
            if (gn < N_NODES) {
                int row = wid ? wid[gn] : gn;
                v = h4[(size_t)row * 32 + q];
            }
            hl4[n * 32 + q] = v;
        }
    }
    __syncthreads();
    int ng = t >> 5, cg = t & 31;
    const float4* hl4 = (const float4*)hl;
    const float4* Wl4 = (const float4*)Wl;
    float4 acc[4];
    #pragma unroll
    for (int i = 0; i < 4; ++i) acc[i] = {0.f, 0.f, 0.f, 0.f};
    for (int k4 = 0; k4 < 32; ++k4) {
        float4 a0 = hl4[(ng * 4 + 0) * 32 + k4];
        float4 a1 = hl4[(ng * 4 + 1) * 32 + k4];
        float4 a2 = hl4[(ng * 4 + 2) * 32 + k4];
        float4 a3 = hl4[(ng * 4 + 3) * 32 + k4];
        #pragma unroll
        for (int kk = 0; kk < 4; ++kk) {
            float4 w = Wl4[(k4 * 4 + kk) * 32 + cg];
            float c0 = ((const float*)&a0)[kk];
            float c1 = ((const float*)&a1)[kk];
            float c2 = ((const float*)&a2)[kk];
            float c3 = ((const float*)&a3)[kk];
            acc[0].x += c0 * w.x; acc[0].y += c0 * w.y; acc[0].z += c0 * w.z; acc[0].w += c0 * w.w;
            acc[1].x += c1 * w.x; acc[1].y += c1 * w.y; acc[1].z += c1 * w.z; acc[1].w += c1 * w.w;
            acc[2].x += c2 * w.x; acc[2].y += c2 * w.y; acc[2].z += c2 * w.z; acc[2].w += c2 * w.w;
            acc[3].x += c3 * w.x; acc[3].y += c3 * w.y; acc[3].z += c3 * w.z; acc[3].w += c3 * w.w;
        }
    }
    int hd = cg >> 3;            // head of this 4-channel group
    float a0v = al[cg * 4], a1v = al[cg * 4 + 1], a2v = al[cg * 4 + 2], a3v = al[cg * 4 + 3];
    float r0v = ar[cg * 4], r1v = ar[cg * 4 + 1], r2v = ar[cg * 4 + 2], r3v = ar[cg * 4 + 3];
    #pragma unroll
    for (int i = 0; i < 4; ++i) {
        int n = n0 + ng * 4 + i;
        if (n >= N_NODES) break;             // uniform across the 8-lane head group
        uint2 pk;
        pk.x = pack_bf2(acc[i].x, acc[i].y);
        pk.y = pack_bf2(acc[i].z, acc[i].w);
        *(uint2*)(featb + (size_t)n * 64 + cg * 2) = pk;
        float pl = acc[i].x * a0v + acc[i].y * a1v + acc[i].z * a2v + acc[i].w * a3v;
        float pr = acc[i].x * r0v + acc[i].y * r1v + acc[i].z * r2v + acc[i].w * r3v;
        #pragma unroll
        for (int off = 1; off < 8; off <<= 1) {
            pl += __shfl_xor(pl, off, 64);
            pr += __shfl_xor(pr, off, 64);
        }
        if ((t & 7) == 0) {
            el[n * 4 + hd] = pl * LOG2E;     // pre-scaled for exp2 in aggregate
            er[n * 4 + hd] = pr * LOG2E;
        }
    }
}

// Fused softmax + aggregation + ELU. One 64-lane wave per dst node.
// 16 lanes per edge, 4 edges per wave-iter (8 with unroll). Each lane owns
// 8 channels [8li, 8li+8) via ONE uint4 load (16 B/lane). exp redundancy 4x.
// No cross-lane ops in the loop; 2 shfl_xor rounds (16,32) at the end.
__global__ void gat_aggregate(const int* __restrict__ row_start, const int* __restrict__ csr_src,
                              const unsigned* __restrict__ featb, const float* __restrict__ el,
                              const float* __restrict__ er, float* __restrict__ hout) {
    int lane = threadIdx.x & 63;
    int d = blockIdx.x * 4 + (threadIdx.x >> 6);
    int beg = row_start[d], end = row_start[d + 1];
    int eg = lane >> 4;          // edge slot 0..3
    int li = lane & 15;          // channel group: channels [8li, 8li+8)
    int hc = li >> 2;            // head of these channels
    float er_h = er[d * 4 + hc];
    float a0 = 0.f, a1 = 0.f, a2 = 0.f, a3 = 0.f;
    float a4 = 0.f, a5 = 0.f, a6 = 0.f, a7 = 0.f;
    float dsum = 0.f;
    int b8 = beg + ((end - beg) & ~7);
    for (int base = beg; base < b8; base += 8) {
        int ea = base + eg, eb = base + 4 + eg;
        int sa = csr_src[ea];
        int sb = csr_src[eb];
        float la = el[sa * 4 + hc];
        float lb = el[sb * 4 + hc];
        uint4 pa = *(const uint4*)(featb + (size_t)sa * 64 + li * 4);
        uint4 pb = *(const uint4*)(featb + (size_t)sb * 64 + li * 4);
        float va = la + er_h; va = fmaxf(va, NEG_SLOPE * va);
        float vb = lb + er_h; vb = fmaxf(vb, NEG_SLOPE * vb);
        float xa = exp2f(va), xb = exp2f(vb);
        dsum += xa + xb;
        a0 += __uint_as_float(pa.x << 16) * xa;
        a1 += __uint_as_float(pa.x & 0xFFFF0000u) * xa;
        a2 += __uint_as_float(pa.y << 16) * xa;
        a3 += __uint_as_float(pa.y & 0xFFFF0000u) * xa;
        a4 += __uint_as_float(pa.z << 16) * xa;
        a5 += __uint_as_float(pa.z & 0xFFFF0000u) * xa;
        a6 += __uint_as_float(pa.w << 16) * xa;
        a7 += __uint_as_float(pa.w & 0xFFFF0000u) * xa;
        a0 += __uint_as_float(pb.x << 16) * xb;
        a1 += __uint_as_float(pb.x & 0xFFFF0000u) * xb;
        a2 += __uint_as_float(pb.y << 16) * xb;
        a3 += __uint_as_float(pb.y & 0xFFFF0000u) * xb;
        a4 += __uint_as_float(pb.z << 16) * xb;
        a5 += __uint_as_float(pb.z & 0xFFFF0000u) * xb;
        a6 += __uint_as_float(pb.w << 16) * xb;
        a7 += __uint_as_float(pb.w & 0xFFFF0000u) * xb;
    }
    for (int ee = b8 + eg; ee < end; ee += 4) {
        int s = csr_src[ee];
        float lv = el[s * 4 + hc];
        uint4 pv = *(const uint4*)(featb + (size_t)s * 64 + li * 4);
        float v = lv + er_h; v = fmaxf(v, NEG_SLOPE * v);
        float x = exp2f(v);
        dsum += x;
        a0 += __uint_as_float(pv.x << 16) * x;
        a1 += __uint_as_float(pv.x & 0xFFFF0000u) * x;
        a2 += __uint_as_float(pv.y << 16) * x;
        a3 += __uint_as_float(pv.y & 0xFFFF0000u) * x;
        a4 += __uint_as_float(pv.z << 16) * x;
        a5 += __uint_as_float(pv.z & 0xFFFF0000u) * x;
        a6 += __uint_as_float(pv.w << 16) * x;
        a7 += __uint_as_float(pv.w & 0xFFFF0000u) * x;
    }
    // combine the 4 edge-slots (lanes with equal li hold the same channels)
    #pragma unroll
    for (int off = 16; off < 64; off <<= 1) {
        a0 += __shfl_xor(a0, off, 64);
        a1 += __shfl_xor(a1, off, 64);
        a2 += __shfl_xor(a2, off, 64);
        a3 += __shfl_xor(a3, off, 64);
        a4 += __shfl_xor(a4, off, 64);
        a5 += __shfl_xor(a5, off, 64);
        a6 += __shfl_xor(a6, off, 64);
        a7 += __shfl_xor(a7, off, 64);
        dsum += __shfl_xor(dsum, off, 64);
    }
    if (eg == 0) {
        float inv = 1.f / (dsum + 1e-10f);
        float o0 = a0 * inv, o1 = a1 * inv, o2 = a2 * inv, o3 = a3 * inv;
        float o4 = a4 * inv, o5 = a5 * inv, o6 = a6 * inv, o7 = a7 * inv;
        o0 = o0 > 0.f ? o0 : expm1f(o0);
        o1 = o1 > 0.f ? o1 : expm1f(o1);
        o2 = o2 > 0.f ? o2 : expm1f(o2);
        o3 = o3 > 0.f ? o3 : expm1f(o3);
        o4 = o4 > 0.f ? o4 : expm1f(o4);
        o5 = o5 > 0.f ? o5 : expm1f(o5);
        o6 = o6 > 0.f ? o6 : expm1f(o6);
        o7 = o7 > 0.f ? o7 : expm1f(o7);
        float4* op = (float4*)(hout + (size_t)d * 128);
        float4 w0 = {o0, o1, o2, o3};
        float4 w1 = {o4, o5, o6, o7};
        op[li * 2] = w0;
        op[li * 2 + 1] = w1;
    }
}

// ---------------- pooling / loss ----------------

__global__ void pool_kernel(const int* __restrict__ gid, const float* __restrict__ h,
                            unsigned* __restrict__ pkeys) {
    int t = threadIdx.x;
    int c = t & 127;
    int par = t >> 7;              // 0/1
    int n0 = blockIdx.x * POOL_CHUNK;
    float m = 0.f;
    int cur_g = -1;
    for (int n = n0 + par; n < n0 + POOL_CHUNK; n += 2) {
        int g = gid[n];
        if (g != cur_g) {
            if (cur_g >= 0) atomicMax(&pkeys[cur_g * 128 + c], fkey(m));
            cur_g = g;
            m = -3.0e38f;
        }
        m = fmaxf(m, h[(size_t)n * 128 + c]);
    }
    if (cur_g >= 0) atomicMax(&pkeys[cur_g * 128 + c], fkey(m));
}

__global__ void logits_kernel(const unsigned* __restrict__ pkeys, const float* __restrict__ w,
                              const float* __restrict__ bptr, float* __restrict__ logits) {
    int g = blockIdx.x, t = threadIdx.x;      // 64 blocks x 64 threads
    float sum = 0.f;
    for (int c = t; c < 128; c += 64) {
        unsigned k = pkeys[g * 128 + c];
        float v = (k == 0u) ? 0.f : kval(k);
        sum += v * w[c];
    }
    #pragma unroll
    for (int off = 32; off; off >>= 1) sum += __shfl_down(sum, off, 64);
    if (t == 0) logits[g] = sum + bptr[0];
}

__global__ void final_kernel(const float* __restrict__ logits, const float* __restrict__ y,
                             float* __restrict__ out) {
    int t = threadIdx.x;  // 64
    float l = logits[t];
    float term = fmaxf(l, 0.f) - l * y[t] + log1pf(expf(-fabsf(l)));
    float s = term;
    #pragma unroll
    for (int off = 32; off; off >>= 1) s += __shfl_down(s, off, 64);
    out[1 + t] = 1.f / (1.f + expf(-l));
    if (t == 0) out[0] = s * (1.f / 64.f);
}

extern "C" void kernel_launch(void* const* d_in, const int* in_sizes, int n_in,
                              void* d_out, int out_size, void* d_ws, size_t ws_size,
                              hipStream_t stream) {
    const int* word_ids  = (const int*)d_in[0];
    const int* esrc      = (const int*)d_in[1];
    const int* edst      = (const int*)d_in[2];
    const int* gid       = (const int*)d_in[3];
    const float* y_data  = (const float*)d_in[4];
    const float* emb     = (const float*)d_in[5];
    const float* W0      = (const float*)d_in[6];
    const float* al0     = (const float*)d_in[7];
    const float* ar0     = (const float*)d_in[8];
    const float* W1      = (const float*)d_in[9];
    const float* al1     = (const float*)d_in[10];
    const float* ar1     = (const float*)d_in[11];
    const float* out_w   = (const float*)d_in[12];
    const float* out_b   = (const float*)d_in[13];
    float* out = (float*)d_out;

    // workspace layout (float offsets); ~47 MB total
    float* ws = (float*)d_ws;
    unsigned* featb  = (unsigned*)ws;                // N*64 uints = 3,200,000
    float*    hbuf   = ws + 3200000;                 // N*128 = 6,400,000
    float*    el     = ws + 9600000;                 // 200,000
    float*    er     = ws + 9800000;                 // 200,000
    int*      row_st = (int*)(ws + 10000000);        // 50,001
    int*      deg    = (int*)(ws + 10051000);        // 50,000
    int*      rank   = (int*)(ws + 10101000);        // 800,000
    int*      csrsrc = (int*)(ws + 10901000);        // 800,000
    int*      partial= (int*)(ws + 11701000);        // 196
    unsigned* pkeys  = (unsigned*)(ws + 11701400);   // 8,192
    float*    logits = ws + 11709592;                // 64

    // CSR build (shared by both layers)
    hipMemsetAsync(deg, 0, (size_t)N_NODES * 4, stream);
    hist_kernel<<<EDGE_NB, 256, 0, stream>>>(edst, deg, rank);
    partial_kernel<<<SCAN_NB, 256, 0, stream>>>(deg, partial);
    csr_offsets_kernel<<<SCAN_NB, 256, 0, stream>>>(deg, partial, row_st);
    scatter_kernel<<<EDGE_NB, 256, 0, stream>>>(esrc, edst, rank, row_st, csrsrc);

    // layer 0 (gather fused into feat staging), then layer 1
    feat_kernel<<<FEAT_NB, 256, 0, stream>>>(emb, word_ids, W0, al0, ar0, featb, el, er);
    gat_aggregate<<<12500, 256, 0, stream>>>(row_st, csrsrc, featb, el, er, hbuf);
    feat_kernel<<<FEAT_NB, 256, 0, stream>>>(hbuf, nullptr, W1, al1, ar1, featb, el, er);
    gat_aggregate<<<12500, 256, 0, stream>>>(row_st, csrsrc, featb, el, er, hbuf);

    hipMemsetAsync(pkeys, 0, (size_t)N_GRAPHS * 128 * 4, stream);
    pool_kernel<<<POOL_NB, 256, 0, stream>>>(gid, hbuf, pkeys);
    logits_kernel<<<N_GRAPHS, 64, 0, stream>>>(pkeys, out_w, out_b, logits);
    final_kernel<<<1, 64, 0, stream>>>(logits, y_data, out);
}

// Round 13
// 299.317 us; speedup vs baseline: 1.1373x; 1.1007x over previous
//
#include <hip/hip_runtime.h>
#include <math.h>

#define N_NODES 50000
#define N_EDGES 800000
#define HEADS 4
#define N_GRAPHS 64
#define NEG_SLOPE 0.2f
#define LOG2E 1.4426950408889634f
#define SCAN_NB 196            // 196*256 = 50176 >= N_NODES
#define POOL_CHUNK 200
#define POOL_NB 250            // 250*200 = 50000 exactly
#define FEAT_NB 782            // ceil(50000/64)
#define EDGE_Q 200000          // N_EDGES/4: 4 edges per thread
#define EDGE_NB 782            // ceil(200000/256)

typedef __attribute__((ext_vector_type(8))) short bf16x8;
typedef __attribute__((ext_vector_type(4))) float f32x4;

// monotone float<->uint key for atomicMax-based segment max (pooling).
__device__ __forceinline__ unsigned fkey(float f) {
    unsigned u = __float_as_uint(f);
    return (u & 0x80000000u) ? ~u : (u | 0x80000000u);
}
__device__ __forceinline__ float kval(unsigned k) {
    unsigned u = (k & 0x80000000u) ? (k & 0x7FFFFFFFu) : ~k;
    return __uint_as_float(u);
}

// f32 -> bf16 (RNE), two packed into one uint (lo = first channel)
__device__ __forceinline__ unsigned short f2bf(float f) {
    unsigned u = __float_as_uint(f);
    u += 0x7FFFu + ((u >> 16) & 1u);
    return (unsigned short)(u >> 16);
}
__device__ __forceinline__ unsigned pack_bf2(float a, float b) {
    return (unsigned)f2bf(a) | ((unsigned)f2bf(b) << 16);
}

// ---------------- CSR build (counting sort by dst, rank-based) ----------------

__global__ void hist_kernel(const int* __restrict__ dst, int* __restrict__ deg,
                            int* __restrict__ rank) {
    int i = blockIdx.x * 256 + threadIdx.x;
    if (i >= EDGE_Q) return;
    int e0 = i, e1 = i + EDGE_Q, e2 = i + 2 * EDGE_Q, e3 = i + 3 * EDGE_Q;
    int d0 = dst[e0], d1 = dst[e1], d2 = dst[e2], d3 = dst[e3];
    int r0 = atomicAdd(&deg[d0], 1);
    int r1 = atomicAdd(&deg[d1], 1);
    int r2 = atomicAdd(&deg[d2], 1);
    int r3 = atomicAdd(&deg[d3], 1);
    rank[e0] = r0; rank[e1] = r1; rank[e2] = r2; rank[e3] = r3;
}

__global__ void partial_kernel(const int* __restrict__ deg, int* __restrict__ partial) {
    int t = threadIdx.x, b = blockIdx.x;
    int i = b * 256 + t;
    int v = (i < N_NODES) ? deg[i] : 0;
    #pragma unroll
    for (int off = 1; off < 64; off <<= 1) v += __shfl_xor(v, off, 64);
    __shared__ int wsum[4];
    if ((t & 63) == 0) wsum[t >> 6] = v;
    __syncthreads();
    if (t == 0) partial[b] = wsum[0] + wsum[1] + wsum[2] + wsum[3];
}

__global__ void csr_offsets_kernel(const int* __restrict__ deg, const int* __restrict__ partial,
                                   int* __restrict__ row_start) {
    __shared__ int sb[SCAN_NB];
    __shared__ int wsumA[4];
    __shared__ int wsumB[4];
    int t = threadIdx.x, b = blockIdx.x;
    int lane = t & 63, w = t >> 6;
    {   // exclusive scan of partial -> sb
        int v = (t < SCAN_NB) ? partial[t] : 0;
        int incl = v;
        #pragma unroll
        for (int off = 1; off < 64; off <<= 1) {
            int u = __shfl_up(incl, off, 64);
            if (lane >= off) incl += u;
        }
        if (lane == 63) wsumA[w] = incl;
        __syncthreads();
        int woff = 0;
        #pragma unroll
        for (int k = 0; k < 4; ++k) if (k < w) woff += wsumA[k];
        if (t < SCAN_NB) sb[t] = woff + incl - v;
        __syncthreads();
    }
    int i = b * 256 + t;
    int v = (i < N_NODES) ? deg[i] : 0;
    int incl = v;
    #pragma unroll
    for (int off = 1; off < 64; off <<= 1) {
        int u = __shfl_up(incl, off, 64);
        if (lane >= off) incl += u;
    }
    if (lane == 63) wsumB[w] = incl;
    __syncthreads();
    int woff = sb[b];
    #pragma unroll
    for (int k = 0; k < 4; ++k) if (k < w) woff += wsumB[k];
    int excl = woff + incl - v;
    if (i < N_NODES) row_start[i] = excl;
    else if (i == N_NODES) row_start[i] = excl;   // == N_EDGES
}

__global__ void scatter_kernel(const int* __restrict__ src, const int* __restrict__ dst,
                               const int* __restrict__ rank, const int* __restrict__ row_start,
                               int* __restrict__ csr_src) {
    int i = blockIdx.x * 256 + threadIdx.x;
    if (i >= EDGE_Q) return;
    int e0 = i, e1 = i + EDGE_Q, e2 = i + 2 * EDGE_Q, e3 = i + 3 * EDGE_Q;
    int d0 = dst[e0], d1 = dst[e1], d2 = dst[e2], d3 = dst[e3];
    int k0 = rank[e0], k1 = rank[e1], k2 = rank[e2], k3 = rank[e3];
    int s0 = src[e0], s1 = src[e1], s2 = src[e2], s3 = src[e3];
    csr_src[row_start[d0] + k0] = s0;
    csr_src[row_start[d1] + k1] = s1;
    csr_src[row_start[d2] + k2] = s2;
    csr_src[row_start[d3] + k3] = s3;
}

// ---------------- node pipeline ----------------

// Pre-pack W into MFMA B-fragment lane order (bf16):
// slot = f*64 + lane, f = ct*4+kq, lane = n + 16q:
//   holds W[32kq+8q+j][16ct+n], j=0..7 as 8 bf16 (uint4).
__global__ void wfrag_kernel(const float* __restrict__ W, unsigned* __restrict__ wf) {
    int slot = blockIdx.x * 256 + threadIdx.x;   // 2048 slots exactly (8 blocks)
    int f = slot >> 6, l = slot & 63;
    int n = l & 15, q = l >> 4;
    int ct = f >> 2, kq = f & 3;
    int col = 16 * ct + n;
    int k0 = 32 * kq + 8 * q;
    uint4 o;
    o.x = pack_bf2(W[(k0 + 0) * 128 + col], W[(k0 + 1) * 128 + col]);
    o.y = pack_bf2(W[(k0 + 2) * 128 + col], W[(k0 + 3) * 128 + col]);
    o.z = pack_bf2(W[(k0 + 4) * 128 + col], W[(k0 + 5) * 128 + col]);
    o.w = pack_bf2(W[(k0 + 6) * 128 + col], W[(k0 + 7) * 128 + col]);
    ((uint4*)wf)[slot] = o;
}

// feat = h @ W via MFMA 16x16x32 bf16. 64 nodes/block, 4 waves, wave w owns
// nodes [n0+16w, n0+16w+16). LDS: only the bf16 h-tile (stride 136 bf16 = 68
// uints, 16B-aligned rows). B-frags stream from the pre-packed wf (L2-hot).
// el/er computed from f32 accumulators (C layout col=lane&15,row=quad*4+reg),
// stored pre-scaled by LOG2E. featb packed bf16 via shfl_xor(1) col pairing.
__global__ __launch_bounds__(256)
void feat_kernel(const float* __restrict__ h, const int* __restrict__ wid,
                 const unsigned* __restrict__ wf,
                 const float* __restrict__ al, const float* __restrict__ ar,
                 unsigned* __restrict__ featb, float* __restrict__ el,
                 float* __restrict__ er) {
    __shared__ unsigned hl[64 * 68];     // 17408 B
    int t = threadIdx.x;
    int n0 = blockIdx.x * 64;
    const float4* h4 = (const float4*)h;
    #pragma unroll
    for (int r = 0; r < 8; ++r) {        // 2048 float4 = 64 nodes x 32
        int i = t + 256 * r;
        int n = i >> 5, q4 = i & 31;
        float4 v = {0.f, 0.f, 0.f, 0.f};
        int gn = n0 + n;
        if (gn < N_NODES) {
            int row = wid ? wid[gn] : gn;
            v = h4[(size_t)row * 32 + q4];
        }
        hl[n * 68 + q4 * 2]     = pack_bf2(v.x, v.y);
        hl[n * 68 + q4 * 2 + 1] = pack_bf2(v.z, v.w);
    }
    __syncthreads();
    int w = t >> 6, lane = t & 63;
    int col = lane & 15, quad = lane >> 4;
    int nbase = n0 + 16 * w;
    // A-frags: lane holds h[nbase + (lane&15)][32kq + 8quad + j], j=0..7
    bf16x8 afr[4];
    #pragma unroll
    for (int kq = 0; kq < 4; ++kq)
        afr[kq] = *(const bf16x8*)&hl[(16 * w + col) * 68 + 16 * kq + 4 * quad];
    f32x4 acc[8];
    #pragma unroll
    for (int ct = 0; ct < 8; ++ct) acc[ct] = (f32x4){0.f, 0.f, 0.f, 0.f};
    const uint4* wf4 = (const uint4*)wf;
    #pragma unroll
    for (int ct = 0; ct < 8; ++ct) {
        #pragma unroll
        for (int kq = 0; kq < 4; ++kq) {
            uint4 braw = wf4[(ct * 4 + kq) * 64 + lane];
            bf16x8 bfr = *(const bf16x8*)&braw;
            acc[ct] = __builtin_amdgcn_mfma_f32_16x16x32_bf16(afr[kq], bfr, acc[ct], 0, 0, 0);
        }
    }
    // featb: C/D element (row=quad*4+reg, col=16ct+col); pack col pairs
    #pragma unroll
    for (int ct = 0; ct < 8; ++ct) {
        #pragma unroll
        for (int reg = 0; reg < 4; ++reg) {
            float v = acc[ct][reg];
            float pv = __shfl_xor(v, 1, 64);
            int node = nbase + quad * 4 + reg;
            if (!(col & 1) && node < N_NODES)
                featb[(size_t)node * 64 + ct * 8 + (col >> 1)] = pack_bf2(v, pv);
        }
    }
    // el/er: head hd covers tiles 2hd,2hd+1; reduce over 16 cols of each quad
    float alv[8], arv[8];
    #pragma unroll
    for (int ct = 0; ct < 8; ++ct) {
        alv[ct] = al[ct * 16 + col];
        arv[ct] = ar[ct * 16 + col];
    }
    #pragma unroll
    for (int reg = 0; reg < 4; ++reg) {
        int node = nbase + quad * 4 + reg;
        #pragma unroll
        for (int hd = 0; hd < 4; ++hd) {
            float pl = acc[2 * hd][reg] * alv[2 * hd] + acc[2 * hd + 1][reg] * alv[2 * hd + 1];
            float pr = acc[2 * hd][reg] * arv[2 * hd] + acc[2 * hd + 1][reg] * arv[2 * hd + 1];
            #pragma unroll
            for (int off = 1; off < 16; off <<= 1) {
                pl += __shfl_xor(pl, off, 64);
                pr += __shfl_xor(pr, off, 64);
            }
            if (col == hd && node < N_NODES) {
                el[node * 4 + hd] = pl * LOG2E;
                er[node * 4 + hd] = pr * LOG2E;
            }
        }
    }
}

// Fused softmax + aggregation + ELU. One 64-lane wave per dst node.
// 16 lanes per edge, 4 edges per wave-iter (8 with unroll). Each lane owns
// 8 channels [8li, 8li+8) via ONE uint4 load. exp redundancy 4x.
__global__ void gat_aggregate(const int* __restrict__ row_start, const int* __restrict__ csr_src,
                              const unsigned* __restrict__ featb, const float* __restrict__ el,
                              const float* __restrict__ er, float* __restrict__ hout) {
    int lane = threadIdx.x & 63;
    int d = blockIdx.x * 4 + (threadIdx.x >> 6);
    int beg = row_start[d], end = row_start[d + 1];
    int eg = lane >> 4;          // edge slot 0..3
    int li = lane & 15;          // channel group: channels [8li, 8li+8)
    int hc = li >> 2;            // head of these channels
    float er_h = er[d * 4 + hc];
    float a0 = 0.f, a1 = 0.f, a2 = 0.f, a3 = 0.f;
    float a4 = 0.f, a5 = 0.f, a6 = 0.f, a7 = 0.f;
    float dsum = 0.f;
    int b8 = beg + ((end - beg) & ~7);
    for (int base = beg; base < b8; base += 8) {
        int ea = base + eg, eb = base + 4 + eg;
        int sa = csr_src[ea];
        int sb = csr_src[eb];
        float la = el[sa * 4 + hc];
        float lb = el[sb * 4 + hc];
        uint4 pa = *(const uint4*)(featb + (size_t)sa * 64 + li * 4);
        uint4 pb = *(const uint4*)(featb + (size_t)sb * 64 + li * 4);
        float va = la + er_h; va = fmaxf(va, NEG_SLOPE * va);
        float vb = lb + er_h; vb = fmaxf(vb, NEG_SLOPE * vb);
        float xa = exp2f(va), xb = exp2f(vb);
        dsum += xa + xb;
        a0 += __uint_as_float(pa.x << 16) * xa;
        a1 += __uint_as_float(pa.x & 0xFFFF0000u) * xa;
        a2 += __uint_as_float(pa.y << 16) * xa;
        a3 += __uint_as_float(pa.y & 0xFFFF0000u) * xa;
        a4 += __uint_as_float(pa.z << 16) * xa;
        a5 += __uint_as_float(pa.z & 0xFFFF0000u) * xa;
        a6 += __uint_as_float(pa.w << 16) * xa;
        a7 += __uint_as_float(pa.w & 0xFFFF0000u) * xa;
        a0 += __uint_as_float(pb.x << 16) * xb;
        a1 += __uint_as_float(pb.x & 0xFFFF0000u) * xb;
        a2 += __uint_as_float(pb.y << 16) * xb;
        a3 += __uint_as_float(pb.y & 0xFFFF0000u) * xb;
        a4 += __uint_as_float(pb.z << 16) * xb;
        a5 += __uint_as_float(pb.z & 0xFFFF0000u) * xb;
        a6 += __uint_as_float(pb.w << 16) * xb;
        a7 += __uint_as_float(pb.w & 0xFFFF0000u) * xb;
    }
    for (int ee = b8 + eg; ee < end; ee += 4) {
        int s = csr_src[ee];
        float lv = el[s * 4 + hc];
        uint4 pv = *(const uint4*)(featb + (size_t)s * 64 + li * 4);
        float v = lv + er_h; v = fmaxf(v, NEG_SLOPE * v);
        float x = exp2f(v);
        dsum += x;
        a0 += __uint_as_float(pv.x << 16) * x;
        a1 += __uint_as_float(pv.x & 0xFFFF0000u) * x;
        a2 += __uint_as_float(pv.y << 16) * x;
        a3 += __uint_as_float(pv.y & 0xFFFF0000u) * x;
        a4 += __uint_as_float(pv.z << 16) * x;
        a5 += __uint_as_float(pv.z & 0xFFFF0000u) * x;
        a6 += __uint_as_float(pv.w << 16) * x;
        a7 += __uint_as_float(pv.w & 0xFFFF0000u) * x;
    }
    #pragma unroll
    for (int off = 16; off < 64; off <<= 1) {
        a0 += __shfl_xor(a0, off, 64);
        a1 += __shfl_xor(a1, off, 64);
        a2 += __shfl_xor(a2, off, 64);
        a3 += __shfl_xor(a3, off, 64);
        a4 += __shfl_xor(a4, off, 64);
        a5 += __shfl_xor(a5, off, 64);
        a6 += __shfl_xor(a6, off, 64);
        a7 += __shfl_xor(a7, off, 64);
        dsum += __shfl_xor(dsum, off, 64);
    }
    if (eg == 0) {
        float inv = 1.f / (dsum + 1e-10f);
        float o0 = a0 * inv, o1 = a1 * inv, o2 = a2 * inv, o3 = a3 * inv;
        float o4 = a4 * inv, o5 = a5 * inv, o6 = a6 * inv, o7 = a7 * inv;
        o0 = o0 > 0.f ? o0 : expm1f(o0);
        o1 = o1 > 0.f ? o1 : expm1f(o1);
        o2 = o2 > 0.f ? o2 : expm1f(o2);
        o3 = o3 > 0.f ? o3 : expm1f(o3);
        o4 = o4 > 0.f ? o4 : expm1f(o4);
        o5 = o5 > 0.f ? o5 : expm1f(o5);
        o6 = o6 > 0.f ? o6 : expm1f(o6);
        o7 = o7 > 0.f ? o7 : expm1f(o7);
        float4* op = (float4*)(hout + (size_t)d * 128);
        float4 w0 = {o0, o1, o2, o3};
        float4 w1 = {o4, o5, o6, o7};
        op[li * 2] = w0;
        op[li * 2 + 1] = w1;
    }
}

// ---------------- pooling / loss ----------------

__global__ void pool_kernel(const int* __restrict__ gid, const float* __restrict__ h,
                            unsigned* __restrict__ pkeys) {
    int t = threadIdx.x;
    int c = t & 127;
    int par = t >> 7;              // 0/1
    int n0 = blockIdx.x * POOL_CHUNK;
    float m = 0.f;
    int cur_g = -1;
    for (int n = n0 + par; n < n0 + POOL_CHUNK; n += 2) {
        int g = gid[n];
        if (g != cur_g) {
            if (cur_g >= 0) atomicMax(&pkeys[cur_g * 128 + c], fkey(m));
            cur_g = g;
            m = -3.0e38f;
        }
        m = fmaxf(m, h[(size_t)n * 128 + c]);
    }
    if (cur_g >= 0) atomicMax(&pkeys[cur_g * 128 + c], fkey(m));
}

__global__ void logits_kernel(const unsigned* __restrict__ pkeys, const float* __restrict__ w,
                              const float* __restrict__ bptr, float* __restrict__ logits) {
    int g = blockIdx.x, t = threadIdx.x;      // 64 blocks x 64 threads
    float sum = 0.f;
    for (int c = t; c < 128; c += 64) {
        unsigned k = pkeys[g * 128 + c];
        float v = (k == 0u) ? 0.f : kval(k);
        sum += v * w[c];
    }
    #pragma unroll
    for (int off = 32; off; off >>= 1) sum += __shfl_down(sum, off, 64);
    if (t == 0) logits[g] = sum + bptr[0];
}

__global__ void final_kernel(const float* __restrict__ logits, const float* __restrict__ y,
                             float* __restrict__ out) {
    int t = threadIdx.x;  // 64
    float l = logits[t];
    float term = fmaxf(l, 0.f) - l * y[t] + log1pf(expf(-fabsf(l)));
    float s = term;
    #pragma unroll
    for (int off = 32; off; off >>= 1) s += __shfl_down(s, off, 64);
    out[1 + t] = 1.f / (1.f + expf(-l));
    if (t == 0) out[0] = s * (1.f / 64.f);
}

extern "C" void kernel_launch(void* const* d_in, const int* in_sizes, int n_in,
                              void* d_out, int out_size, void* d_ws, size_t ws_size,
                              hipStream_t stream) {
    const int* word_ids  = (const int*)d_in[0];
    const int* esrc      = (const int*)d_in[1];
    const int* edst      = (const int*)d_in[2];
    const int* gid       = (const int*)d_in[3];
    const float* y_data  = (const float*)d_in[4];
    const float* emb     = (const float*)d_in[5];
    const float* W0      = (const float*)d_in[6];
    const float* al0     = (const float*)d_in[7];
    const float* ar0     = (const float*)d_in[8];
    const float* W1      = (const float*)d_in[9];
    const float* al1     = (const float*)d_in[10];
    const float* ar1     = (const float*)d_in[11];
    const float* out_w   = (const float*)d_in[12];
    const float* out_b   = (const float*)d_in[13];
    float* out = (float*)d_out;

    // workspace layout (float offsets); ~47 MB total
    float* ws = (float*)d_ws;
    unsigned* featb  = (unsigned*)ws;                // N*64 uints = 3,200,000
    float*    hbuf   = ws + 3200000;                 // N*128 = 6,400,000
    float*    el     = ws + 9600000;                 // 200,000
    float*    er     = ws + 9800000;                 // 200,000
    int*      row_st = (int*)(ws + 10000000);        // 50,001
    int*      deg    = (int*)(ws + 10051000);        // 50,000
    int*      rank   = (int*)(ws + 10101000);        // 800,000
    int*      csrsrc = (int*)(ws + 10901000);        // 800,000
    int*      partial= (int*)(ws + 11701000);        // 196
    unsigned* pkeys  = (unsigned*)(ws + 11701400);   // 8,192
    float*    logits = ws + 11709592;                // 64
    unsigned* wfbuf  = (unsigned*)(ws + 11709704);   // 8,192 uints (16B-aligned)

    // CSR build (shared by both layers)
    hipMemsetAsync(deg, 0, (size_t)N_NODES * 4, stream);
    hist_kernel<<<EDGE_NB, 256, 0, stream>>>(edst, deg, rank);
    partial_kernel<<<SCAN_NB, 256, 0, stream>>>(deg, partial);
    csr_offsets_kernel<<<SCAN_NB, 256, 0, stream>>>(deg, partial, row_st);
    scatter_kernel<<<EDGE_NB, 256, 0, stream>>>(esrc, edst, rank, row_st, csrsrc);

    // layer 0 (embedding gather fused into feat staging), then layer 1
    wfrag_kernel<<<8, 256, 0, stream>>>(W0, wfbuf);
    feat_kernel<<<FEAT_NB, 256, 0, stream>>>(emb, word_ids, wfbuf, al0, ar0, featb, el, er);
    gat_aggregate<<<12500, 256, 0, stream>>>(row_st, csrsrc, featb, el, er, hbuf);
    wfrag_kernel<<<8, 256, 0, stream>>>(W1, wfbuf);
    feat_kernel<<<FEAT_NB, 256, 0, stream>>>(hbuf, nullptr, wfbuf, al1, ar1, featb, el, er);
    gat_aggregate<<<12500, 256, 0, stream>>>(row_st, csrsrc, featb, el, er, hbuf);

    hipMemsetAsync(pkeys, 0, (size_t)N_GRAPHS * 128 * 4, stream);
    pool_kernel<<<POOL_NB, 256, 0, stream>>>(gid, hbuf, pkeys);
    logits_kernel<<<N_GRAPHS, 64, 0, stream>>>(pkeys, out_w, out_b, logits);
    final_kernel<<<1, 64, 0, stream>>>(logits, y_data, out);
}